// Round 8
// baseline (266.998 us; speedup 1.0000x reference)
//
#include <hip/hip_runtime.h>

// ---------------------------------------------------------------------------
// TransVLAD fused pipeline for MI355X (gfx950)
// Shapes: N=32, C=512, H=W=32 (P=1024), E=1024, G=8, D=128, K=64
// out: [N, K*D] fp32 (262144)
//
// R8: (a) att folded algebraically: att = sigmoid((W2*W1) * xhat); W2W1
// [8][512] built in k0, att_s from xhat in k3 -> K2 epilogue fusion removed.
// (b) K2 -> one M=1536 GEMM [W1;V]*xhat (W1b,Vb already contiguous) emitting
// xe AND S bf16 -> K4's S-phase (32 staging rounds, 8x xhat re-read) deleted.
// (c) K4' = S-tile DMA + per-pixel softmax + agg MFMA; 12 barriers/block,
// 35.8KB LDS, grid 1024 = 4 blocks/CU. wsum via ones-MFMA.
// agg_part (32MiB) aliases dead xhat slot; total ws 137.4MB < proven 138.9MB.
// ---------------------------------------------------------------------------

#define N_  32
#define C_  512
#define P_  1024
#define E_  1024
#define G_  8
#define D_  128
#define K_  64

typedef __attribute__((ext_vector_type(8))) short bf16x8;
typedef __attribute__((ext_vector_type(4))) float f32x4;

__device__ __forceinline__ unsigned short f2b(float f) {
    union { float f; unsigned u; } v; v.f = f;
    unsigned r = (v.u + 0x7FFFu + ((v.u >> 16) & 1u)) >> 16;
    return (unsigned short)r;
}
__device__ __forceinline__ float b2f(unsigned short h) {
    union { unsigned u; float f; } v; v.u = ((unsigned)h) << 16;
    return v.f;
}

// async global->LDS 16B copy: LDS dest must be wave-uniform base + lane*16
__device__ __forceinline__ void gl_lds16(const void* g, void* l) {
    __builtin_amdgcn_global_load_lds(
        (const __attribute__((address_space(1))) void*)g,
        (__attribute__((address_space(3))) void*)l, 16, 0, 0);
}

// ---------------------------------------------------------------------------
// K0: W1->bf16 (into AB rows 0..1023), V=Wc*W1_g (AB rows 1024..1535),
// and W2W1[g][c] = sum_e W2[g][e]*W1[e][c] (fp32, 4096 vals).
// grid 1088: bid<1024 main; bid>=1024 -> W2W1 (64 blocks, 4 lanes/output).
__global__ __launch_bounds__(256) void k0_prep(const float* __restrict__ W1,
                                               const float* __restrict__ Wc,
                                               const float* __restrict__ W2,
                                               unsigned short* __restrict__ AB,
                                               float* __restrict__ W2W1) {
    int bid = blockIdx.x;
    int t = threadIdx.x;
    if (bid < 1024) {
        int i0 = bid * 512 + t;
        AB[i0]       = f2b(W1[i0]);
        AB[i0 + 256] = f2b(W1[i0 + 256]);
        int ch = bid & 1, k = (bid >> 1) & 63, g = bid >> 7;
        int c = ch * 256 + t;
        float acc = 0.f;
        #pragma unroll 8
        for (int d = 0; d < 128; ++d)
            acc += Wc[k * 128 + d] * W1[(g * 128 + d) * C_ + c];
        AB[(1024 + g * 64 + k) * C_ + c] = f2b(acc);   // V rows appended
    } else {
        int b2 = bid - 1024;                 // 0..63
        int out = b2 * 64 + (t >> 2);        // 0..4095
        int eq = t & 3;
        int g = out >> 9, c = out & 511;
        float acc = 0.f;
        int e0 = eq * 256;
        #pragma unroll 8
        for (int e = e0; e < e0 + 256; ++e)
            acc += W2[g * E_ + e] * W1[e * C_ + c];
        acc += __shfl_xor(acc, 1);
        acc += __shfl_xor(acc, 2);
        if (eq == 0) W2W1[out] = acc;        // layout [g][c]
    }
}

// ---------------------------------------------------------------------------
// K1: per-pixel L2 norm over C, write x_hat transposed: xhat_t [N][P][C] bf16
__global__ __launch_bounds__(256) void k1_norm_transpose(const float* __restrict__ x,
                                                         unsigned short* __restrict__ xhat_t) {
    __shared__ short xc[128 * 256];
    __shared__ float red[256];
    __shared__ float rn[64];
    int n = blockIdx.y;
    int p0 = blockIdx.x * 64;
    int t = threadIdx.x;
    int ps = t & 63, cs = t >> 6;

    float ss = 0.f;
    for (int i = 0; i < 128; ++i) {
        float v = x[((size_t)(n * C_ + cs * 128 + i)) * P_ + p0 + ps];
        ss += v * v;
        xc[i * 256 + t] = (short)f2b(v);
    }
    red[t] = ss;
    __syncthreads();
    if (t < 64) {
        float s = red[t] + red[64 + t] + red[128 + t] + red[192 + t];
        rn[t] = 1.0f / fmaxf(sqrtf(s), 1e-12f);
    }
    __syncthreads();

    float r = rn[ps];
    size_t base = ((size_t)(n * P_ + p0 + ps)) * C_ + cs * 128;
    #pragma unroll
    for (int jj = 0; jj < 16; ++jj) {
        bf16x8 o;
        #pragma unroll
        for (int j = 0; j < 8; ++j)
            o[j] = (short)f2b(b2f((unsigned short)xc[(jj * 8 + j) * 256 + t]) * r);
        *(bf16x8*)&xhat_t[base + jj * 8] = o;
    }
}

// ---------------------------------------------------------------------------
// K2: [xe;S] = AB(1536xC) * xhat^T  (bf16 MFMA, BK=64, 128x128 tiles)
// grid (96, 32): mt = bx>>3 (0..11), p0 = (bx&7)*128, n = by.
// rows <1024 -> xe[n][e][p]; rows >=1024 -> S[n][e-1024][p].
__global__ __launch_bounds__(256) void k2_gemm(const unsigned short* __restrict__ AB,
                                               const unsigned short* __restrict__ xhat_t,
                                               unsigned short* __restrict__ xe,
                                               unsigned short* __restrict__ S) {
    __shared__ __align__(16) short As[128 * 64];
    __shared__ __align__(16) short Bs[128 * 64];
    int n = blockIdx.y;
    int e0 = (blockIdx.x >> 3) * 128;
    int p0 = (blockIdx.x & 7) * 128;
    int t = threadIdx.x;
    int w = t >> 6, l = t & 63, q = l >> 4, l15 = l & 15;
    int wr = w >> 1, wc = w & 1;

    f32x4 acc[4][4];
    #pragma unroll
    for (int mi = 0; mi < 4; ++mi)
        #pragma unroll
        for (int ni = 0; ni < 4; ++ni)
            acc[mi][ni] = (f32x4){0.f, 0.f, 0.f, 0.f};

    for (int ks = 0; ks < 8; ++ks) {
        int k0 = ks * 64;
        #pragma unroll
        for (int i = 0; i < 4; ++i) {
            int ch = i * 256 + t;
            int row = ch >> 3, col = (ch & 7) * 8;
            gl_lds16(&AB[(e0 + row) * C_ + k0 + col], &As[ch * 8]);
        }
        #pragma unroll
        for (int i = 0; i < 4; ++i) {
            int ch = i * 256 + t;
            int row = ch >> 3, col = (ch & 7) * 8;
            gl_lds16(&xhat_t[((size_t)(n * P_ + p0 + row)) * C_ + k0 + col], &Bs[ch * 8]);
        }
        __syncthreads();

        #pragma unroll
        for (int kk = 0; kk < 2; ++kk) {
            bf16x8 af[4], bf[4];
            #pragma unroll
            for (int mi = 0; mi < 4; ++mi)
                af[mi] = *(const bf16x8*)&As[(wr * 64 + mi * 16 + l15) * 64 + kk * 32 + q * 8];
            #pragma unroll
            for (int ni = 0; ni < 4; ++ni)
                bf[ni] = *(const bf16x8*)&Bs[(wc * 64 + ni * 16 + l15) * 64 + kk * 32 + q * 8];
            #pragma unroll
            for (int mi = 0; mi < 4; ++mi)
                #pragma unroll
                for (int ni = 0; ni < 4; ++ni)
                    acc[mi][ni] = __builtin_amdgcn_mfma_f32_16x16x32_bf16(af[mi], bf[ni], acc[mi][ni], 0, 0, 0);
        }
        __syncthreads();
    }

    if (e0 < 1024) {
        #pragma unroll
        for (int mi = 0; mi < 4; ++mi)
            #pragma unroll
            for (int ni = 0; ni < 4; ++ni)
                #pragma unroll
                for (int r = 0; r < 4; ++r) {
                    int e = e0 + wr * 64 + mi * 16 + q * 4 + r;
                    int p = p0 + wc * 64 + ni * 16 + l15;
                    xe[((size_t)(n * E_ + e)) * P_ + p] = f2b(acc[mi][ni][r]);
                }
    } else {
        int s0 = e0 - 1024;
        #pragma unroll
        for (int mi = 0; mi < 4; ++mi)
            #pragma unroll
            for (int ni = 0; ni < 4; ++ni)
                #pragma unroll
                for (int r = 0; r < 4; ++r) {
                    int sr = s0 + wr * 64 + mi * 16 + q * 4 + r;
                    int p = p0 + wc * 64 + ni * 16 + l15;
                    S[((size_t)(n * 512 + sr)) * P_ + p] = f2b(acc[mi][ni][r]);
                }
    }
}

// ---------------------------------------------------------------------------
// K3: att_s[n][g][p] = sigmoid( sum_c W2W1[g][c] * xhat[p][c] )
// grid (16, 32): px0 = bx*64; 4 lanes per pixel (qc = c-quarter).
__global__ __launch_bounds__(256) void k3_att(const unsigned short* __restrict__ xhat_t,
                                              const float* __restrict__ W2W1,
                                              float* __restrict__ att_s) {
    __shared__ float w2l[512 * 8];   // [c][g] 16 KB
    int n = blockIdx.y;
    int t = threadIdx.x;
    #pragma unroll
    for (int i = 0; i < 16; ++i) {
        int idx = i * 256 + t;               // c = idx>>3, g = idx&7
        w2l[idx] = W2W1[(idx & 7) * C_ + (idx >> 3)];
    }
    __syncthreads();

    int px = blockIdx.x * 64 + (t >> 2);
    int qc = t & 3;
    const unsigned short* xrow = &xhat_t[((size_t)(n * P_ + px)) * C_ + qc * 128];
    f32x4 a0 = {0.f, 0.f, 0.f, 0.f}, a1 = {0.f, 0.f, 0.f, 0.f};
    #pragma unroll 4
    for (int j = 0; j < 16; ++j) {
        bf16x8 xv = *(const bf16x8*)&xrow[j * 8];
        #pragma unroll
        for (int ee = 0; ee < 8; ++ee) {
            float v = b2f((unsigned short)xv[ee]);
            int c = qc * 128 + j * 8 + ee;
            a0 += v * *(const f32x4*)&w2l[c * 8];
            a1 += v * *(const f32x4*)&w2l[c * 8 + 4];
        }
    }
    #pragma unroll
    for (int gg = 0; gg < 4; ++gg) {
        a0[gg] += __shfl_xor(a0[gg], 1); a0[gg] += __shfl_xor(a0[gg], 2);
        a1[gg] += __shfl_xor(a1[gg], 1); a1[gg] += __shfl_xor(a1[gg], 2);
    }
    if (qc == 0) {
        #pragma unroll
        for (int gg = 0; gg < 4; ++gg) {
            att_s[((size_t)(n * G_ + gg)) * P_ + px]     = 1.0f / (1.0f + __expf(-a0[gg]));
            att_s[((size_t)(n * G_ + gg + 4)) * P_ + px] = 1.0f / (1.0f + __expf(-a1[gg]));
        }
    }
}

// ---------------------------------------------------------------------------
// K4: softmax + gate + aggregation per (n, g, qt). grid (32, 32): qt=bx&3,
// g=bx>>2. 2 cc iters of 128 px. LDS 35840 B -> 4 blocks/CU.
__global__ __launch_bounds__(256) void k4_assign_agg(const unsigned short* __restrict__ S,
                                                     const unsigned short* __restrict__ xe,
                                                     const float* __restrict__ att_s,
                                                     float* __restrict__ agg_part,
                                                     float* __restrict__ wsum_part) {
    __shared__ __align__(16) char smem[18432 + 17408];
    short* slds  = (short*)smem;                // [64][136] 17.4 KB (S tile)
    short* xglds = (short*)smem;                // [128][72] 18 KB (aliases slds)
    short* wlds  = (short*)(smem + 18432);      // [64][136] 17.4 KB

    int qt = blockIdx.x & 3, g = blockIdx.x >> 2, n = blockIdx.y;
    int t = threadIdx.x;
    int w = t >> 6, l = t & 63, q = l >> 4, l15 = l & 15;

    const short ONE = (short)0x3F80;            // bf16 1.0
    bf16x8 ones = {ONE, ONE, ONE, ONE, ONE, ONE, ONE, ONE};

    f32x4 acc_a[4][2];
    #pragma unroll
    for (int mi = 0; mi < 4; ++mi)
        #pragma unroll
        for (int ni = 0; ni < 2; ++ni)
            acc_a[mi][ni] = (f32x4){0.f, 0.f, 0.f, 0.f};
    f32x4 acc_w[4];
    #pragma unroll
    for (int mi = 0; mi < 4; ++mi) acc_w[mi] = (f32x4){0.f, 0.f, 0.f, 0.f};

    for (int cc = 0; cc < 2; ++cc) {
        int p0c = qt * 256 + cc * 128;

        // ---- stage S tile [64k][128p] (17 chunks/row incl. pad) ----
        #pragma unroll
        for (int i = 0; i < 4; ++i) {
            int ch = i * 256 + t;
            int row = ch / 17, col = (ch % 17) * 8;
            gl_lds16(&S[((size_t)(n * 512 + g * 64 + row)) * P_ + p0c + col], &slds[ch * 8]);
        }
        if (t < 64) {
            int ch = 1024 + t;
            int row = ch / 17, col = (ch % 17) * 8;
            gl_lds16(&S[((size_t)(n * 512 + g * 64 + row)) * P_ + p0c + col], &slds[ch * 8]);
        }
        __syncthreads();

        // ---- per-pixel softmax over 64 k + gate (threads 0..127) ----
        if (t < 128) {
            float m = -1e30f;
            #pragma unroll 8
            for (int k = 0; k < 64; ++k)
                m = fmaxf(m, b2f((unsigned short)slds[k * 136 + t]));
            float s = 0.f;
            float av = att_s[((size_t)(n * G_ + g)) * P_ + p0c + t];
            // two-pass: exp-sum first (keep in LDS write pass after scale known)
            #pragma unroll 8
            for (int k = 0; k < 64; ++k)
                s += __expf(b2f((unsigned short)slds[k * 136 + t]) - m);
            float scale = av / s;
            #pragma unroll 8
            for (int k = 0; k < 64; ++k) {
                float wv = __expf(b2f((unsigned short)slds[k * 136 + t]) - m) * scale;
                wlds[k * 136 + t] = (short)f2b(wv);
            }
        }
        __syncthreads();   // wlds ready; slds dead

        // ---- agg in two 64-px halves: stage xglds (aliases slds) + MFMA ----
        for (int h = 0; h < 2; ++h) {
            #pragma unroll
            for (int i = 0; i < 4; ++i) {
                int ch = i * 256 + t;
                int row = ch / 9, col = (ch % 9) * 8;
                gl_lds16(&xe[((size_t)(n * E_ + g * 128 + row)) * P_ + p0c + h * 64 + col],
                         &xglds[ch * 8]);
            }
            if (t < 128) {
                int ch = 1024 + t;
                int row = ch / 9, col = (ch % 9) * 8;
                gl_lds16(&xe[((size_t)(n * E_ + g * 128 + row)) * P_ + p0c + h * 64 + col],
                         &xglds[ch * 8]);
            }
            __syncthreads();

            #pragma unroll
            for (int pk = 0; pk < 2; ++pk) {
                bf16x8 a2[4], b2[2];
                #pragma unroll
                for (int mi = 0; mi < 4; ++mi)
                    a2[mi] = *(const bf16x8*)&wlds[(mi * 16 + l15) * 136 + h * 64 + pk * 32 + q * 8];
                #pragma unroll
                for (int ni = 0; ni < 2; ++ni)
                    b2[ni] = *(const bf16x8*)&xglds[(w * 32 + ni * 16 + l15) * 72 + pk * 32 + q * 8];
                #pragma unroll
                for (int mi = 0; mi < 4; ++mi) {
                    #pragma unroll
                    for (int ni = 0; ni < 2; ++ni)
                        acc_a[mi][ni] = __builtin_amdgcn_mfma_f32_16x16x32_bf16(a2[mi], b2[ni], acc_a[mi][ni], 0, 0, 0);
                    acc_w[mi] = __builtin_amdgcn_mfma_f32_16x16x32_bf16(a2[mi], ones, acc_w[mi], 0, 0, 0);
                }
            }
            __syncthreads();
        }
    }

    // ---- epilogue: disjoint partials ----
    size_t base = (((size_t)(n * G_ + g)) * 4 + qt) * 64;
    #pragma unroll
    for (int mi = 0; mi < 4; ++mi)
        #pragma unroll
        for (int ni = 0; ni < 2; ++ni)
            #pragma unroll
            for (int r = 0; r < 4; ++r) {
                int k = mi * 16 + q * 4 + r;
                int d = w * 32 + ni * 16 + l15;
                agg_part[(base + k) * 128 + d] = acc_a[mi][ni][r];
            }
    if (w == 0 && l15 == 0) {   // acc_w identical across waves; cols identical
        #pragma unroll
        for (int mi = 0; mi < 4; ++mi)
            #pragma unroll
            for (int r = 0; r < 4; ++r)
                wsum_part[base + mi * 16 + q * 4 + r] = acc_w[mi][r];
    }
}

// k4c: wsum[n][k] = sum over (g, qt)
__global__ __launch_bounds__(256) void k4c_wsum(const float* __restrict__ wsum_part,
                                                float* __restrict__ wsum) {
    int idx = blockIdx.x * 256 + threadIdx.x;   // grid 8 -> 2048
    int n = idx >> 6, k = idx & 63;
    float s = 0.f;
    #pragma unroll
    for (int g = 0; g < 8; ++g)
        #pragma unroll
        for (int qt = 0; qt < 4; ++qt)
            s += wsum_part[(((size_t)(n * G_ + g)) * 4 + qt) * 64 + k];
    wsum[idx] = s;
}

// ---------------------------------------------------------------------------
// K5: vlad[n][k][d] = sum_{g,qt} agg_part - wsum[n][k] * centroids[k][d]
__global__ __launch_bounds__(256) void k5_final(const float* __restrict__ agg_part,
                                                const float* __restrict__ wsum,
                                                const float* __restrict__ centroids,
                                                float* __restrict__ out) {
    int idx = blockIdx.x * 256 + threadIdx.x;   // grid 1024 -> 262144
    int d = idx & 127;
    int k = (idx >> 7) & 63;
    int n = idx >> 13;
    float ag = 0.f;
    #pragma unroll
    for (int g = 0; g < 8; ++g)
        #pragma unroll
        for (int qt = 0; qt < 4; ++qt)
            ag += agg_part[((((size_t)(n * G_ + g)) * 4 + qt) * 64 + k) * 128 + d];
    out[idx] = ag - wsum[n * 64 + k] * centroids[k * 128 + d];
}

// ---------------------------------------------------------------------------
extern "C" void kernel_launch(void* const* d_in, const int* in_sizes, int n_in,
                              void* d_out, int out_size, void* d_ws, size_t ws_size,
                              hipStream_t stream) {
    const float* x         = (const float*)d_in[0];
    const float* W1        = (const float*)d_in[1];
    const float* W2        = (const float*)d_in[2];
    const float* Wc        = (const float*)d_in[3];
    const float* centroids = (const float*)d_in[4];
    float* out = (float*)d_out;

    // Workspace layout (total 137,388,032 B < proven 138,944,512 B):
    //   AB = [W1b;Vb] [1536][512] bf16  1,572,864 B @ 0
    //   xhat_t  [N][P][C]  bf16  33,554,432 B @ 1,572,864  (dead after k3_att;
    //   agg_part[N][G][4][K][D] f32 33,554,432 B @ 1,572,864  exact alias)
    //   xe      [N][E][P]  bf16  67,108,864 B @ 35,127,296
    //   att_s   [N][G][P]  f32    1,048,576 B @ 102,236,160
    //   S       [N][512][P] bf16 33,554,432 B @ 103,284,736
    //   wsum_part [N][G][4][K] f32  524,288 B @ 136,839,168
    //   wsum    [N][K]     f32        8,192 B @ 137,363,456
    //   W2W1    [8][512]   f32       16,384 B @ 137,371,648
    char* ws = (char*)d_ws;
    unsigned short* AB       = (unsigned short*)(ws + 0);
    unsigned short* xhat_t   = (unsigned short*)(ws + 1572864);
    float*          agg_part = (float*)(ws + 1572864);     // alias: xhat dead before k4
    unsigned short* xe       = (unsigned short*)(ws + 35127296);
    float*          att_s    = (float*)(ws + 102236160);
    unsigned short* S        = (unsigned short*)(ws + 103284736);
    float*          wsum_part= (float*)(ws + 136839168);
    float*          wsum     = (float*)(ws + 137363456);
    float*          W2W1     = (float*)(ws + 137371648);

    hipLaunchKernelGGL(k0_prep,        dim3(1088), dim3(256), 0, stream, W1, Wc, W2, AB, W2W1);
    hipLaunchKernelGGL(k1_norm_transpose, dim3(16, 32), dim3(256), 0, stream, x, xhat_t);
    hipLaunchKernelGGL(k2_gemm,        dim3(96, 32), dim3(256), 0, stream, AB, xhat_t, xe, S);
    hipLaunchKernelGGL(k3_att,         dim3(16, 32), dim3(256), 0, stream, xhat_t, W2W1, att_s);
    hipLaunchKernelGGL(k4_assign_agg,  dim3(32, 32), dim3(256), 0, stream, S, xe,
                       att_s, agg_part, wsum_part);
    hipLaunchKernelGGL(k4c_wsum,       dim3(8), dim3(256), 0, stream, wsum_part, wsum);
    hipLaunchKernelGGL(k5_final,       dim3(1024), dim3(256), 0, stream,
                       agg_part, wsum, centroids, out);
}